// Round 6
// baseline (324.587 us; speedup 1.0000x reference)
//
#include <hip/hip_runtime.h>

// TransformerBlockQuantum: attention(Q=K=V=x) -> LN1 -> quantum FFN -> LN2
// Round 9: fusion reverted (k_hid restored; computeA chain was serial inside
// the barrier window at 2 blocks/CU -- R8 post-mortem). k_prep+k_cvt merged
// into one dispatch (~9us launch overhead each). k_gemm re-tiled to 64x128
// blocks (grid 1024), single-buffered 24KB LDS, m97-style 2-barrier loop,
// launch_bounds(256,4) -> 4 blocks/CU (16 waves/CU, 2x occupancy).

#define Bq 4
#define Sq 2048
#define Eq 1024
#define Hq 16
#define DKq 64
#define FFNq 4096
#define NQq 8
#define LOG2E 1.44269504f

typedef unsigned int u32;
typedef unsigned short u16;
typedef _Float16 f16;
typedef f16 f16x8 __attribute__((ext_vector_type(8)));
typedef __fp16 fp16x2 __attribute__((ext_vector_type(2)));
typedef float f32x4 __attribute__((ext_vector_type(4)));

#if __has_builtin(__builtin_amdgcn_exp2f)
#define EXP2F __builtin_amdgcn_exp2f
#else
#define EXP2F exp2f
#endif

#define MFMA(a, b, c) __builtin_amdgcn_mfma_f32_16x16x32_f16((a), (b), (c), 0, 0, 0)

// async global->LDS, 16B per lane; LDS dest = base + lane*16 (wave-uniform base)
#define GLL(g, l)                                                          \
  __builtin_amdgcn_global_load_lds(                                        \
      (const __attribute__((address_space(1))) u32*)(g),                   \
      (__attribute__((address_space(3))) u32*)(l), 16, 0, 0)

__device__ __forceinline__ u16 f2h(float x) {
  f16 t = (f16)x;
  return __builtin_bit_cast(u16, t);
}
__device__ __forceinline__ float h2f(u16 w) {
  return (float)__builtin_bit_cast(f16, w);
}
#if __has_builtin(__builtin_amdgcn_cvt_pkrtz)
__device__ __forceinline__ u32 pkrtz(float a, float b) {
  fp16x2 r = __builtin_amdgcn_cvt_pkrtz(a, b);
  return __builtin_bit_cast(u32, r);
}
#else
__device__ __forceinline__ u32 pkrtz(float a, float b) {
  return (u32)f2h(a) | ((u32)f2h(b) << 16);
}
#endif

union F8 { f16x8 v; u32 w[4]; u16 h[8]; f16 e[8]; };

// ------- merged prep: blocks [0,2048): x fp32 -> xh fp16 + xt fp16
//                      blocks [2048,4096): w2 fp32 -> fp16 ----------
__global__ void k_prep(const float* __restrict__ x, u16* __restrict__ xh,
                       u16* __restrict__ xt, const float* __restrict__ w2src,
                       uint4* __restrict__ w2dst) {
  __shared__ u16 tile[64 * 72];
  const int tid = threadIdx.x;
  const int bx = blockIdx.x;
  if (bx >= 2048) {
    // ---- w2 converter path ----
    const int i = (bx - 2048) * 256 + tid;
    const int n8 = (Eq * FFNq) / 8;
    if (i < n8) {
      const float4* s = (const float4*)w2src + 2 * (long)i;
      float4 a = s[0], b = s[1];
      uint4 r;
      r.x = pkrtz(a.x, a.y);
      r.y = pkrtz(a.z, a.w);
      r.z = pkrtz(b.x, b.y);
      r.w = pkrtz(b.z, b.w);
      w2dst[i] = r;
    }
    return;
  }
  const int sb = bx & 31, bh = bx >> 5;
  const int b = bh >> 4, h = bh & 15;
  const int s0 = sb * 64;
  const int r = tid >> 2, cq = tid & 3;
  const float* xp = x + ((long)(b * Sq + s0 + r)) * Eq + h * 64 + cq * 16;
  float4 f0 = ((const float4*)xp)[0], f1 = ((const float4*)xp)[1];
  float4 f2 = ((const float4*)xp)[2], f3 = ((const float4*)xp)[3];
  u32 w[8];
  w[0] = pkrtz(f0.x, f0.y); w[1] = pkrtz(f0.z, f0.w);
  w[2] = pkrtz(f1.x, f1.y); w[3] = pkrtz(f1.z, f1.w);
  w[4] = pkrtz(f2.x, f2.y); w[5] = pkrtz(f2.z, f2.w);
  w[6] = pkrtz(f3.x, f3.y); w[7] = pkrtz(f3.z, f3.w);
  uint4* xo = (uint4*)(xh + ((long)(b * Sq + s0 + r)) * Eq + h * 64 + cq * 16);
  xo[0] = make_uint4(w[0], w[1], w[2], w[3]);
  xo[1] = make_uint4(w[4], w[5], w[6], w[7]);
  uint4* tp = (uint4*)(tile + r * 72 + cq * 16);
  tp[0] = make_uint4(w[0], w[1], w[2], w[3]);
  tp[1] = make_uint4(w[4], w[5], w[6], w[7]);
  __syncthreads();
  const int d = tid >> 2, rq = tid & 3;
  u32 o[8];
#pragma unroll
  for (int i = 0; i < 8; ++i) {
    u32 lo = tile[(rq * 16 + 2 * i) * 72 + d];
    u32 hi = tile[(rq * 16 + 2 * i + 1) * 72 + d];
    o[i] = lo | (hi << 16);
  }
  uint4* to = (uint4*)(xt + ((long)(bh * 64 + d)) * Sq + s0 + rq * 16);
  to[0] = make_uint4(o[0], o[1], o[2], o[3]);
  to[1] = make_uint4(o[4], o[5], o[6], o[7]);
}

// ---------------- flash attention (round-4 structure, proven 80.1 us) --------
// grid 512 = qb(8) x bh(64); 8 waves / 512 threads; each wave owns 32 q-rows.
// Double-buffered K/V via GLL, ONE barrier per k-block.
__global__ __launch_bounds__(512, 4) void k_attn(const u16* __restrict__ xh,
                                                 const u16* __restrict__ xt,
                                                 u16* __restrict__ attn) {
  __shared__ __align__(16) u16 lds[32768];  // 2 x (Kl 8KB | Vt 8KB) + P 32KB
  u16* Pl = lds + 16384;

  const int tid = threadIdx.x;
  const int wave = tid >> 6, lane = tid & 63;
  const int n = lane & 15, quad = lane >> 4;

  const int bx = blockIdx.x;
  const int qb = bx >> 6, bh = bx & 63;
  const int b = bh >> 4, h = bh & 15;

  const u16* xh_bh = xh + (long)b * Sq * Eq + h * 64;  // row stride Eq halves
  const u16* xt_bh = xt + (long)bh * 64 * Sq;          // row stride Sq halves

  const float SC = 0.125f * LOG2E;
  F8 qf[2][2];
  float shift[2], lrow[2] = {0.f, 0.f};
#pragma unroll
  for (int nt = 0; nt < 2; ++nt) {
    const int q = qb * 256 + wave * 32 + nt * 16 + n;
    const u16* qp = xh_bh + (long)q * Eq + quad * 8;
    F8 a, c;
    a.v = *(const f16x8*)qp;
    c.v = *(const f16x8*)(qp + 32);
    float s2 = 0.f;
#pragma unroll
    for (int i = 0; i < 8; ++i) {
      float va = (float)a.e[i], vc = (float)c.e[i];
      s2 += va * va + vc * vc;
      qf[nt][0].e[i] = a.e[i] * (f16)SC;
      qf[nt][1].e[i] = c.e[i] * (f16)SC;
    }
    s2 += __shfl_xor(s2, 16);
    s2 += __shfl_xor(s2, 32);
    shift[nt] = SC * s2;  // diagonal score in log2 domain
  }

  const int r8 = lane >> 3;
  const int cl = (lane & 7) ^ r8;
  const u16* gK = xh_bh + (long)(wave * 8 + r8) * Eq + cl * 8;
  const u16* gV = xt_bh + (long)(wave * 8 + r8) * Sq + cl * 8;
  const int lK = wave * 512;
  const int lV = 4096 + wave * 512;

  u16* cur = lds;
  u16* nxt = lds + 8192;

  GLL(gK, cur + lK);
  GLL(gV, cur + lV);
  gK += 64 * Eq;
  gV += 64;

  f32x4 O[2][4] = {};
  u16* Pw = Pl + wave * 2048;

  for (int kb = 0; kb < Sq / 64; ++kb) {
    __syncthreads();
    if (kb < Sq / 64 - 1) {
      GLL(gK, nxt + lK);
      GLL(gV, nxt + lV);
      gK += 64 * Eq;
      gV += 64;
    }
    u16* Kl = cur;
    u16* Vt = cur + 4096;

    f32x4 ST[2][4];
#pragma unroll
    for (int nt = 0; nt < 2; ++nt) {
      const float ms = -shift[nt];
#pragma unroll
      for (int mt = 0; mt < 4; ++mt) {
        ST[nt][mt][0] = ms; ST[nt][mt][1] = ms;
        ST[nt][mt][2] = ms; ST[nt][mt][3] = ms;
      }
    }
    __builtin_amdgcn_s_setprio(1);
#pragma unroll
    for (int mt = 0; mt < 4; ++mt) {
#pragma unroll
      for (int c = 0; c < 2; ++c) {
        f16x8 af = *(const f16x8*)(Kl + (mt * 16 + n) * 64 +
                                   (((c * 4 + quad) ^ (n & 7)) * 8));
#pragma unroll
        for (int nt = 0; nt < 2; ++nt)
          ST[nt][mt] = MFMA(af, qf[nt][c].v, ST[nt][mt]);
      }
    }
    __builtin_amdgcn_s_setprio(0);

#pragma unroll
    for (int nt = 0; nt < 2; ++nt) {
      float ls = 0.f;
#pragma unroll
      for (int mt = 0; mt < 4; ++mt) {
        float p0 = EXP2F(ST[nt][mt][0]);
        float p1 = EXP2F(ST[nt][mt][1]);
        float p2 = EXP2F(ST[nt][mt][2]);
        float p3 = EXP2F(ST[nt][mt][3]);
        ls += (p0 + p1) + (p2 + p3);
        const int ch = 2 * mt + (quad >> 1);
        *(uint2*)(Pw + nt * 1024 + n * 64 + ((ch ^ (n & 7)) * 8) + (quad & 1) * 4) =
            make_uint2(pkrtz(p0, p1), pkrtz(p2, p3));
      }
      lrow[nt] += ls;
    }

    __builtin_amdgcn_s_setprio(1);
#pragma unroll
    for (int c = 0; c < 2; ++c) {
      const int pc = ((c * 4 + quad) ^ (n & 7)) * 8;
      f16x8 pf[2];
#pragma unroll
      for (int nt = 0; nt < 2; ++nt)
        pf[nt] = *(const f16x8*)(Pw + nt * 1024 + n * 64 + pc);
#pragma unroll
      for (int dt = 0; dt < 4; ++dt) {
        f16x8 vf = *(const f16x8*)(Vt + (dt * 16 + n) * 64 + pc);
#pragma unroll
        for (int nt = 0; nt < 2; ++nt) O[nt][dt] = MFMA(vf, pf[nt], O[nt][dt]);
      }
    }
    __builtin_amdgcn_s_setprio(0);
    u16* t = cur; cur = nxt; nxt = t;
  }

#pragma unroll
  for (int nt = 0; nt < 2; ++nt) {
    float l = lrow[nt];
    l += __shfl_xor(l, 16);
    l += __shfl_xor(l, 32);
    const float inv = 1.0f / l;
    const int q = qb * 256 + wave * 32 + nt * 16 + n;
    u16* op = attn + (long)b * Sq * Eq + (long)q * Eq + h * 64;
#pragma unroll
    for (int dt = 0; dt < 4; ++dt) {
      u32 w0 = pkrtz(O[nt][dt][0] * inv, O[nt][dt][1] * inv);
      u32 w1 = pkrtz(O[nt][dt][2] * inv, O[nt][dt][3] * inv);
      *(uint2*)(op + dt * 16 + quad * 4) = make_uint2(w0, w1);
    }
  }
}

// ---------------- LN1 (+residual) + quantum qout (all fp16 IO) ----------------
__global__ void k_ln1(const u16* __restrict__ xh, const u16* __restrict__ attn,
                      const float* __restrict__ g, const float* __restrict__ be,
                      const float* __restrict__ theta, u16* __restrict__ hout,
                      u16* __restrict__ qout) {
  const long t = blockIdx.x;
  const int tid = threadIdx.x;
  uint2 xw = ((const uint2*)(xh + t * Eq))[tid];
  uint2 aw = ((const uint2*)(attn + t * Eq))[tid];
  float v0 = h2f(xw.x & 0xffff) + h2f(aw.x & 0xffff);
  float v1 = h2f(xw.x >> 16) + h2f(aw.x >> 16);
  float v2 = h2f(xw.y & 0xffff) + h2f(aw.y & 0xffff);
  float v3 = h2f(xw.y >> 16) + h2f(aw.y >> 16);
  float s = (v0 + v1) + (v2 + v3);
  float s2 = v0 * v0 + v1 * v1 + v2 * v2 + v3 * v3;
#pragma unroll
  for (int o = 1; o < 64; o <<= 1) {
    s += __shfl_xor(s, o);
    s2 += __shfl_xor(s2, o);
  }
  __shared__ float red[8];
  const int wv = tid >> 6, ln = tid & 63;
  if (ln == 0) { red[wv] = s; red[4 + wv] = s2; }
  __syncthreads();
  s = red[0] + red[1] + red[2] + red[3];
  s2 = red[4] + red[5] + red[6] + red[7];
  const float mu = s * (1.f / Eq);
  const float var = s2 * (1.f / Eq) - mu * mu;
  const float rstd = rsqrtf(var + 1e-5f);
  float4 gv = ((const float4*)g)[tid];
  float4 bv = ((const float4*)be)[tid];
  float o0 = (v0 - mu) * rstd * gv.x + bv.x;
  float o1 = (v1 - mu) * rstd * gv.y + bv.y;
  float o2 = (v2 - mu) * rstd * gv.z + bv.z;
  float o3 = (v3 - mu) * rstd * gv.w + bv.w;
  ((uint2*)(hout + t * Eq))[tid] = make_uint2(pkrtz(o0, o1), pkrtz(o2, o3));
  if (tid < 2) {
    float hv[4] = {o0, o1, o2, o3};
    float q[4];
#pragma unroll
    for (int i = 0; i < 4; ++i) q[i] = cosf(hv[i]) * cosf(theta[tid * 4 + i]);
    *(uint2*)(qout + t * NQq + tid * 4) = make_uint2(pkrtz(q[0], q[1]), pkrtz(q[2], q[3]));
  }
}

// ---------------- hid = relu(qout . w1^T + b1), fp16 out ----------------
__global__ void k_hid(const u16* __restrict__ qout, const float* __restrict__ w1,
                      const float* __restrict__ b1, u16* __restrict__ hid) {
  __shared__ float qs[256][8];
  const int tid = threadIdx.x;
  const int fb = blockIdx.x & 63, tb = blockIdx.x >> 6;
  const int f0 = fb * 64, t0 = tb * 256;
  {
    uint4 qw = *(const uint4*)(qout + (long)(t0 + tid) * NQq);
    qs[tid][0] = h2f(qw.x & 0xffff); qs[tid][1] = h2f(qw.x >> 16);
    qs[tid][2] = h2f(qw.y & 0xffff); qs[tid][3] = h2f(qw.y >> 16);
    qs[tid][4] = h2f(qw.z & 0xffff); qs[tid][5] = h2f(qw.z >> 16);
    qs[tid][6] = h2f(qw.w & 0xffff); qs[tid][7] = h2f(qw.w >> 16);
  }
  __syncthreads();
  const int wave = tid >> 6, lane = tid & 63;
  const int f = f0 + lane;
  const float4* wp = (const float4*)(w1 + (long)f * NQq);
  float4 wa = wp[0], wb = wp[1];
  const float bb = b1[f];
  const int trow = wave * 64;
  u16* op = hid + (long)(t0 + trow) * FFNq + f;
#pragma unroll 4
  for (int i = 0; i < 64; ++i) {
    const float* q = qs[trow + i];
    float acc = bb + q[0] * wa.x + q[1] * wa.y + q[2] * wa.z + q[3] * wa.w +
                q[4] * wb.x + q[5] * wb.y + q[6] * wb.z + q[7] * wb.w;
    acc = fmaxf(acc, 0.f);
    op[(long)i * FFNq] = f2h(acc);
  }
}

// ---------------- GEMM: ffn[8192,1024] = hid x w2^T, fp16 out ----------------
// 64x128 tile (grid 1024 = 4 blocks/CU), BK=64; SINGLE 24KB LDS buffer,
// m97-style 2-barrier loop {GLL -> barrier -> compute -> barrier}.
// 4 waves, wave tile 64m x 32n (acc 4x2).
__global__ __launch_bounds__(256, 4) void k_gemm(const u16* __restrict__ Ah,
                                                 const u16* __restrict__ Bh,
                                                 u16* __restrict__ C) {
  __shared__ __align__(16) u16 lds[12288];  // La 8KB (64x64) | Lb 16KB (128x64)
  const int tid = threadIdx.x;
  const int wave = tid >> 6, lane = tid & 63;
  const int n = lane & 15, quad = lane >> 4;
  const int m0 = (blockIdx.x >> 3) * 64;
  const int n0 = (blockIdx.x & 7) * 128;  // bid&7 = n-tile: round-robin XCD
  const int r8 = lane >> 3;
  const int cl = (lane & 7) ^ r8;

  // staging: A 64 rows (wave stages rows wave*16+{0,8}+r8),
  //          B 128 rows (wave stages rows wave*32+{0,8,16,24}+r8)
  const u16* gA0 = Ah + (long)(m0 + wave * 16 + r8) * FFNq + cl * 8;
  const u16* gA1 = gA0 + 8 * FFNq;
  const int lA0 = (wave * 16) * 64, lA1 = (wave * 16 + 8) * 64;
  const u16* gB[4];
  int lB[4];
#pragma unroll
  for (int u = 0; u < 4; ++u) {
    const int row = wave * 32 + u * 8;
    gB[u] = Bh + (long)(n0 + row + r8) * FFNq + cl * 8;
    lB[u] = 4096 + row * 64;
  }

  f32x4 acc[4][2] = {};
  for (int it = 0; it < FFNq / 64; ++it) {
    GLL(gA0, lds + lA0);
    GLL(gA1, lds + lA1);
#pragma unroll
    for (int u = 0; u < 4; ++u) GLL(gB[u], lds + lB[u]);
    gA0 += 64; gA1 += 64;
#pragma unroll
    for (int u = 0; u < 4; ++u) gB[u] += 64;
    __syncthreads();  // drain GLL -> tile ready
    u16* La = lds;
    u16* Lb = lds + 4096;
#pragma unroll
    for (int c = 0; c < 2; ++c) {
      const int sw = ((c * 4 + quad) ^ (n & 7)) * 8;
      f16x8 af[4], bf[2];
#pragma unroll
      for (int i = 0; i < 4; ++i)
        af[i] = *(const f16x8*)(La + (i * 16 + n) * 64 + sw);
#pragma unroll
      for (int j = 0; j < 2; ++j)
        bf[j] = *(const f16x8*)(Lb + (wave * 32 + j * 16 + n) * 64 + sw);
#pragma unroll
      for (int i = 0; i < 4; ++i)
#pragma unroll
        for (int j = 0; j < 2; ++j) acc[i][j] = MFMA(af[i], bf[j], acc[i][j]);
    }
    __syncthreads();  // compute done -> buffer reusable
  }
#pragma unroll
  for (int i = 0; i < 4; ++i) {
    const int row = m0 + i * 16 + quad * 4;
#pragma unroll
    for (int j = 0; j < 2; ++j) {
      u16* cp = C + (long)row * Eq + n0 + wave * 32 + j * 16 + n;
      cp[0] = f2h(acc[i][j][0]);
      cp[Eq] = f2h(acc[i][j][1]);
      cp[2 * Eq] = f2h(acc[i][j][2]);
      cp[3 * Eq] = f2h(acc[i][j][3]);
    }
  }
}

// ---------------- LN2: out = LN(h + ffn + b2), fp32 out ----------------
__global__ void k_ln2(const u16* __restrict__ hin, const u16* __restrict__ ffn,
                      const float* __restrict__ b2, const float* __restrict__ g,
                      const float* __restrict__ be, float* __restrict__ out) {
  const long t = blockIdx.x;
  const int tid = threadIdx.x;
  uint2 hw = ((const uint2*)(hin + t * Eq))[tid];
  uint2 fw = ((const uint2*)(ffn + t * Eq))[tid];
  float4 b2v = ((const float4*)b2)[tid];
  float v0 = h2f(hw.x & 0xffff) + h2f(fw.x & 0xffff) + b2v.x;
  float v1 = h2f(hw.x >> 16) + h2f(fw.x >> 16) + b2v.y;
  float v2 = h2f(hw.y & 0xffff) + h2f(fw.y & 0xffff) + b2v.z;
  float v3 = h2f(hw.y >> 16) + h2f(fw.y >> 16) + b2v.w;
  float s = (v0 + v1) + (v2 + v3);
  float s2 = v0 * v0 + v1 * v1 + v2 * v2 + v3 * v3;
#pragma unroll
  for (int o = 1; o < 64; o <<= 1) {
    s += __shfl_xor(s, o);
    s2 += __shfl_xor(s2, o);
  }
  __shared__ float red[8];
  const int wv = tid >> 6, ln = tid & 63;
  if (ln == 0) { red[wv] = s; red[4 + wv] = s2; }
  __syncthreads();
  s = red[0] + red[1] + red[2] + red[3];
  s2 = red[4] + red[5] + red[6] + red[7];
  const float mu = s * (1.f / Eq);
  const float var = s2 * (1.f / Eq) - mu * mu;
  const float rstd = rsqrtf(var + 1e-5f);
  float4 gv = ((const float4*)g)[tid];
  float4 bv = ((const float4*)be)[tid];
  float4 o;
  o.x = (v0 - mu) * rstd * gv.x + bv.x;
  o.y = (v1 - mu) * rstd * gv.y + bv.y;
  o.z = (v2 - mu) * rstd * gv.z + bv.z;
  o.w = (v3 - mu) * rstd * gv.w + bv.w;
  ((float4*)(out + t * Eq))[tid] = o;
}

extern "C" void kernel_launch(void* const* d_in, const int* in_sizes, int n_in,
                              void* d_out, int out_size, void* d_ws, size_t ws_size,
                              hipStream_t stream) {
  const float* x = (const float*)d_in[0];
  const float* theta = (const float*)d_in[1];
  const float* w1 = (const float*)d_in[2];
  const float* b1 = (const float*)d_in[3];
  const float* w2 = (const float*)d_in[4];
  const float* b2 = (const float*)d_in[5];
  const float* g1 = (const float*)d_in[6];
  const float* be1 = (const float*)d_in[7];
  const float* g2 = (const float*)d_in[8];
  const float* be2 = (const float*)d_in[9];
  float* out = (float*)d_out;

  char* ws = (char*)d_ws;
  u16* attn = (u16*)(ws);                      // 16 MB
  u16* h = (u16*)(ws + 16777216);              // 16 MB
  u16* xh = (u16*)(ws + 33554432);             // 16 MB
  u16* xt = (u16*)(ws + 50331648);             // 16 MB
  u16* ffn = (u16*)(ws + 67108864);            // 16 MB
  u16* hid = (u16*)(ws + 83886080);            // 64 MB
  u16* w2h = (u16*)(ws + 150994944);           //  8 MB
  u16* qout = (u16*)(ws + 159383552);          // 128 KB

  k_prep<<<2 * Bq * Hq * (Sq / 64), 256, 0, stream>>>(x, xh, xt, w2, (uint4*)w2h);
  k_attn<<<Bq * Hq * (Sq / 256), 512, 0, stream>>>(xh, xt, attn);
  k_ln1<<<Bq * Sq, 256, 0, stream>>>(xh, attn, g1, be1, theta, h, qout);
  k_hid<<<(Bq * Sq / 256) * (FFNq / 64), 256, 0, stream>>>(qout, w1, b1, hid);
  k_gemm<<<(Bq * Sq / 64) * (Eq / 128), 256, 0, stream>>>(hid, w2h, ffn);
  k_ln2<<<Bq * Sq, 256, 0, stream>>>(h, ffn, b2, g2, be2, out);
}

// Round 7
// 301.618 us; speedup vs baseline: 1.0762x; 1.0762x over previous
//
#include <hip/hip_runtime.h>

// TransformerBlockQuantum: attention(Q=K=V=x) -> LN1 -> quantum FFN -> LN2
// Round 10: k_gemm restored to the proven 128x128 BK=64 double-buffered GLL
// structure, now with (1) XCD-aware block swizzle (all 8 n-blocks of an
// A-panel on one XCD -> A fetched once per XCD, 512MB->64MB) and (2) 8 waves
// / 512 threads (wave tile 64x32) -> 16 waves/CU (2x occupancy) at the same
// 64KB LDS. attn/prep/ln1/hid/ln2 unchanged from round 9.

#define Bq 4
#define Sq 2048
#define Eq 1024
#define Hq 16
#define DKq 64
#define FFNq 4096
#define NQq 8
#define LOG2E 1.44269504f

typedef unsigned int u32;
typedef unsigned short u16;
typedef _Float16 f16;
typedef f16 f16x8 __attribute__((ext_vector_type(8)));
typedef __fp16 fp16x2 __attribute__((ext_vector_type(2)));
typedef float f32x4 __attribute__((ext_vector_type(4)));

#if __has_builtin(__builtin_amdgcn_exp2f)
#define EXP2F __builtin_amdgcn_exp2f
#else
#define EXP2F exp2f
#endif

#define MFMA(a, b, c) __builtin_amdgcn_mfma_f32_16x16x32_f16((a), (b), (c), 0, 0, 0)

// async global->LDS, 16B per lane; LDS dest = base + lane*16 (wave-uniform base)
#define GLL(g, l)                                                          \
  __builtin_amdgcn_global_load_lds(                                        \
      (const __attribute__((address_space(1))) u32*)(g),                   \
      (__attribute__((address_space(3))) u32*)(l), 16, 0, 0)

__device__ __forceinline__ u16 f2h(float x) {
  f16 t = (f16)x;
  return __builtin_bit_cast(u16, t);
}
__device__ __forceinline__ float h2f(u16 w) {
  return (float)__builtin_bit_cast(f16, w);
}
#if __has_builtin(__builtin_amdgcn_cvt_pkrtz)
__device__ __forceinline__ u32 pkrtz(float a, float b) {
  fp16x2 r = __builtin_amdgcn_cvt_pkrtz(a, b);
  return __builtin_bit_cast(u32, r);
}
#else
__device__ __forceinline__ u32 pkrtz(float a, float b) {
  return (u32)f2h(a) | ((u32)f2h(b) << 16);
}
#endif

union F8 { f16x8 v; u32 w[4]; u16 h[8]; f16 e[8]; };

// ------- merged prep: blocks [0,2048): x fp32 -> xh fp16 + xt fp16
//                      blocks [2048,4096): w2 fp32 -> fp16 ----------
__global__ void k_prep(const float* __restrict__ x, u16* __restrict__ xh,
                       u16* __restrict__ xt, const float* __restrict__ w2src,
                       uint4* __restrict__ w2dst) {
  __shared__ u16 tile[64 * 72];
  const int tid = threadIdx.x;
  const int bx = blockIdx.x;
  if (bx >= 2048) {
    const int i = (bx - 2048) * 256 + tid;
    const int n8 = (Eq * FFNq) / 8;
    if (i < n8) {
      const float4* s = (const float4*)w2src + 2 * (long)i;
      float4 a = s[0], b = s[1];
      uint4 r;
      r.x = pkrtz(a.x, a.y);
      r.y = pkrtz(a.z, a.w);
      r.z = pkrtz(b.x, b.y);
      r.w = pkrtz(b.z, b.w);
      w2dst[i] = r;
    }
    return;
  }
  const int sb = bx & 31, bh = bx >> 5;
  const int b = bh >> 4, h = bh & 15;
  const int s0 = sb * 64;
  const int r = tid >> 2, cq = tid & 3;
  const float* xp = x + ((long)(b * Sq + s0 + r)) * Eq + h * 64 + cq * 16;
  float4 f0 = ((const float4*)xp)[0], f1 = ((const float4*)xp)[1];
  float4 f2 = ((const float4*)xp)[2], f3 = ((const float4*)xp)[3];
  u32 w[8];
  w[0] = pkrtz(f0.x, f0.y); w[1] = pkrtz(f0.z, f0.w);
  w[2] = pkrtz(f1.x, f1.y); w[3] = pkrtz(f1.z, f1.w);
  w[4] = pkrtz(f2.x, f2.y); w[5] = pkrtz(f2.z, f2.w);
  w[6] = pkrtz(f3.x, f3.y); w[7] = pkrtz(f3.z, f3.w);
  uint4* xo = (uint4*)(xh + ((long)(b * Sq + s0 + r)) * Eq + h * 64 + cq * 16);
  xo[0] = make_uint4(w[0], w[1], w[2], w[3]);
  xo[1] = make_uint4(w[4], w[5], w[6], w[7]);
  uint4* tp = (uint4*)(tile + r * 72 + cq * 16);
  tp[0] = make_uint4(w[0], w[1], w[2], w[3]);
  tp[1] = make_uint4(w[4], w[5], w[6], w[7]);
  __syncthreads();
  const int d = tid >> 2, rq = tid & 3;
  u32 o[8];
#pragma unroll
  for (int i = 0; i < 8; ++i) {
    u32 lo = tile[(rq * 16 + 2 * i) * 72 + d];
    u32 hi = tile[(rq * 16 + 2 * i + 1) * 72 + d];
    o[i] = lo | (hi << 16);
  }
  uint4* to = (uint4*)(xt + ((long)(bh * 64 + d)) * Sq + s0 + rq * 16);
  to[0] = make_uint4(o[0], o[1], o[2], o[3]);
  to[1] = make_uint4(o[4], o[5], o[6], o[7]);
}

// ---------------- flash attention (round-4 structure, proven 80.1 us) --------
__global__ __launch_bounds__(512, 4) void k_attn(const u16* __restrict__ xh,
                                                 const u16* __restrict__ xt,
                                                 u16* __restrict__ attn) {
  __shared__ __align__(16) u16 lds[32768];  // 2 x (Kl 8KB | Vt 8KB) + P 32KB
  u16* Pl = lds + 16384;

  const int tid = threadIdx.x;
  const int wave = tid >> 6, lane = tid & 63;
  const int n = lane & 15, quad = lane >> 4;

  const int bx = blockIdx.x;
  const int qb = bx >> 6, bh = bx & 63;
  const int b = bh >> 4, h = bh & 15;

  const u16* xh_bh = xh + (long)b * Sq * Eq + h * 64;  // row stride Eq halves
  const u16* xt_bh = xt + (long)bh * 64 * Sq;          // row stride Sq halves

  const float SC = 0.125f * LOG2E;
  F8 qf[2][2];
  float shift[2], lrow[2] = {0.f, 0.f};
#pragma unroll
  for (int nt = 0; nt < 2; ++nt) {
    const int q = qb * 256 + wave * 32 + nt * 16 + n;
    const u16* qp = xh_bh + (long)q * Eq + quad * 8;
    F8 a, c;
    a.v = *(const f16x8*)qp;
    c.v = *(const f16x8*)(qp + 32);
    float s2 = 0.f;
#pragma unroll
    for (int i = 0; i < 8; ++i) {
      float va = (float)a.e[i], vc = (float)c.e[i];
      s2 += va * va + vc * vc;
      qf[nt][0].e[i] = a.e[i] * (f16)SC;
      qf[nt][1].e[i] = c.e[i] * (f16)SC;
    }
    s2 += __shfl_xor(s2, 16);
    s2 += __shfl_xor(s2, 32);
    shift[nt] = SC * s2;  // diagonal score in log2 domain
  }

  const int r8 = lane >> 3;
  const int cl = (lane & 7) ^ r8;
  const u16* gK = xh_bh + (long)(wave * 8 + r8) * Eq + cl * 8;
  const u16* gV = xt_bh + (long)(wave * 8 + r8) * Sq + cl * 8;
  const int lK = wave * 512;
  const int lV = 4096 + wave * 512;

  u16* cur = lds;
  u16* nxt = lds + 8192;

  GLL(gK, cur + lK);
  GLL(gV, cur + lV);
  gK += 64 * Eq;
  gV += 64;

  f32x4 O[2][4] = {};
  u16* Pw = Pl + wave * 2048;

  for (int kb = 0; kb < Sq / 64; ++kb) {
    __syncthreads();
    if (kb < Sq / 64 - 1) {
      GLL(gK, nxt + lK);
      GLL(gV, nxt + lV);
      gK += 64 * Eq;
      gV += 64;
    }
    u16* Kl = cur;
    u16* Vt = cur + 4096;

    f32x4 ST[2][4];
#pragma unroll
    for (int nt = 0; nt < 2; ++nt) {
      const float ms = -shift[nt];
#pragma unroll
      for (int mt = 0; mt < 4; ++mt) {
        ST[nt][mt][0] = ms; ST[nt][mt][1] = ms;
        ST[nt][mt][2] = ms; ST[nt][mt][3] = ms;
      }
    }
    __builtin_amdgcn_s_setprio(1);
#pragma unroll
    for (int mt = 0; mt < 4; ++mt) {
#pragma unroll
      for (int c = 0; c < 2; ++c) {
        f16x8 af = *(const f16x8*)(Kl + (mt * 16 + n) * 64 +
                                   (((c * 4 + quad) ^ (n & 7)) * 8));
#pragma unroll
        for (int nt = 0; nt < 2; ++nt)
          ST[nt][mt] = MFMA(af, qf[nt][c].v, ST[nt][mt]);
      }
    }
    __builtin_amdgcn_s_setprio(0);

#pragma unroll
    for (int nt = 0; nt < 2; ++nt) {
      float ls = 0.f;
#pragma unroll
      for (int mt = 0; mt < 4; ++mt) {
        float p0 = EXP2F(ST[nt][mt][0]);
        float p1 = EXP2F(ST[nt][mt][1]);
        float p2 = EXP2F(ST[nt][mt][2]);
        float p3 = EXP2F(ST[nt][mt][3]);
        ls += (p0 + p1) + (p2 + p3);
        const int ch = 2 * mt + (quad >> 1);
        *(uint2*)(Pw + nt * 1024 + n * 64 + ((ch ^ (n & 7)) * 8) + (quad & 1) * 4) =
            make_uint2(pkrtz(p0, p1), pkrtz(p2, p3));
      }
      lrow[nt] += ls;
    }

    __builtin_amdgcn_s_setprio(1);
#pragma unroll
    for (int c = 0; c < 2; ++c) {
      const int pc = ((c * 4 + quad) ^ (n & 7)) * 8;
      f16x8 pf[2];
#pragma unroll
      for (int nt = 0; nt < 2; ++nt)
        pf[nt] = *(const f16x8*)(Pw + nt * 1024 + n * 64 + pc);
#pragma unroll
      for (int dt = 0; dt < 4; ++dt) {
        f16x8 vf = *(const f16x8*)(Vt + (dt * 16 + n) * 64 + pc);
#pragma unroll
        for (int nt = 0; nt < 2; ++nt) O[nt][dt] = MFMA(vf, pf[nt], O[nt][dt]);
      }
    }
    __builtin_amdgcn_s_setprio(0);
    u16* t = cur; cur = nxt; nxt = t;
  }

#pragma unroll
  for (int nt = 0; nt < 2; ++nt) {
    float l = lrow[nt];
    l += __shfl_xor(l, 16);
    l += __shfl_xor(l, 32);
    const float inv = 1.0f / l;
    const int q = qb * 256 + wave * 32 + nt * 16 + n;
    u16* op = attn + (long)b * Sq * Eq + (long)q * Eq + h * 64;
#pragma unroll
    for (int dt = 0; dt < 4; ++dt) {
      u32 w0 = pkrtz(O[nt][dt][0] * inv, O[nt][dt][1] * inv);
      u32 w1 = pkrtz(O[nt][dt][2] * inv, O[nt][dt][3] * inv);
      *(uint2*)(op + dt * 16 + quad * 4) = make_uint2(w0, w1);
    }
  }
}

// ---------------- LN1 (+residual) + quantum qout (all fp16 IO) ----------------
__global__ void k_ln1(const u16* __restrict__ xh, const u16* __restrict__ attn,
                      const float* __restrict__ g, const float* __restrict__ be,
                      const float* __restrict__ theta, u16* __restrict__ hout,
                      u16* __restrict__ qout) {
  const long t = blockIdx.x;
  const int tid = threadIdx.x;
  uint2 xw = ((const uint2*)(xh + t * Eq))[tid];
  uint2 aw = ((const uint2*)(attn + t * Eq))[tid];
  float v0 = h2f(xw.x & 0xffff) + h2f(aw.x & 0xffff);
  float v1 = h2f(xw.x >> 16) + h2f(aw.x >> 16);
  float v2 = h2f(xw.y & 0xffff) + h2f(aw.y & 0xffff);
  float v3 = h2f(xw.y >> 16) + h2f(aw.y >> 16);
  float s = (v0 + v1) + (v2 + v3);
  float s2 = v0 * v0 + v1 * v1 + v2 * v2 + v3 * v3;
#pragma unroll
  for (int o = 1; o < 64; o <<= 1) {
    s += __shfl_xor(s, o);
    s2 += __shfl_xor(s2, o);
  }
  __shared__ float red[8];
  const int wv = tid >> 6, ln = tid & 63;
  if (ln == 0) { red[wv] = s; red[4 + wv] = s2; }
  __syncthreads();
  s = red[0] + red[1] + red[2] + red[3];
  s2 = red[4] + red[5] + red[6] + red[7];
  const float mu = s * (1.f / Eq);
  const float var = s2 * (1.f / Eq) - mu * mu;
  const float rstd = rsqrtf(var + 1e-5f);
  float4 gv = ((const float4*)g)[tid];
  float4 bv = ((const float4*)be)[tid];
  float o0 = (v0 - mu) * rstd * gv.x + bv.x;
  float o1 = (v1 - mu) * rstd * gv.y + bv.y;
  float o2 = (v2 - mu) * rstd * gv.z + bv.z;
  float o3 = (v3 - mu) * rstd * gv.w + bv.w;
  ((uint2*)(hout + t * Eq))[tid] = make_uint2(pkrtz(o0, o1), pkrtz(o2, o3));
  if (tid < 2) {
    float hv[4] = {o0, o1, o2, o3};
    float q[4];
#pragma unroll
    for (int i = 0; i < 4; ++i) q[i] = cosf(hv[i]) * cosf(theta[tid * 4 + i]);
    *(uint2*)(qout + t * NQq + tid * 4) = make_uint2(pkrtz(q[0], q[1]), pkrtz(q[2], q[3]));
  }
}

// ---------------- hid = relu(qout . w1^T + b1), fp16 out ----------------
__global__ void k_hid(const u16* __restrict__ qout, const float* __restrict__ w1,
                      const float* __restrict__ b1, u16* __restrict__ hid) {
  __shared__ float qs[256][8];
  const int tid = threadIdx.x;
  const int fb = blockIdx.x & 63, tb = blockIdx.x >> 6;
  const int f0 = fb * 64, t0 = tb * 256;
  {
    uint4 qw = *(const uint4*)(qout + (long)(t0 + tid) * NQq);
    qs[tid][0] = h2f(qw.x & 0xffff); qs[tid][1] = h2f(qw.x >> 16);
    qs[tid][2] = h2f(qw.y & 0xffff); qs[tid][3] = h2f(qw.y >> 16);
    qs[tid][4] = h2f(qw.z & 0xffff); qs[tid][5] = h2f(qw.z >> 16);
    qs[tid][6] = h2f(qw.w & 0xffff); qs[tid][7] = h2f(qw.w >> 16);
  }
  __syncthreads();
  const int wave = tid >> 6, lane = tid & 63;
  const int f = f0 + lane;
  const float4* wp = (const float4*)(w1 + (long)f * NQq);
  float4 wa = wp[0], wb = wp[1];
  const float bb = b1[f];
  const int trow = wave * 64;
  u16* op = hid + (long)(t0 + trow) * FFNq + f;
#pragma unroll 4
  for (int i = 0; i < 64; ++i) {
    const float* q = qs[trow + i];
    float acc = bb + q[0] * wa.x + q[1] * wa.y + q[2] * wa.z + q[3] * wa.w +
                q[4] * wb.x + q[5] * wb.y + q[6] * wb.z + q[7] * wb.w;
    acc = fmaxf(acc, 0.f);
    op[(long)i * FFNq] = f2h(acc);
  }
}

// ---------------- GEMM: ffn[8192,1024] = hid x w2^T, fp16 out ----------------
// 128x128 tile, BK=64, double-buffered GLL, one barrier per k-iter.
// 8 waves / 512 threads (wave tile 64x32) -> 16 waves/CU at 64KB LDS.
// XCD swizzle: xcd = bid&7 owns m-panels [xcd*8, xcd*8+8) x all n -> each
// A-panel fetched by exactly one XCD.
__global__ __launch_bounds__(512, 4) void k_gemm(const u16* __restrict__ Ah,
                                                 const u16* __restrict__ Bh,
                                                 u16* __restrict__ C) {
  __shared__ __align__(16) u16 lds[32768];  // 2 x (La 16KB | Lb 16KB)
  const int tid = threadIdx.x;
  const int wave = tid >> 6, lane = tid & 63;
  const int n = lane & 15, quad = lane >> 4;
  const int wm = wave >> 2, wn = wave & 3;
  const int bid = blockIdx.x;
  const int m0 = ((bid & 7) * 8 + (bid >> 6)) * 128;  // same-A blocks -> same XCD
  const int n0 = ((bid >> 3) & 7) * 128;
  const int r8 = lane >> 3;
  const int cl = (lane & 7) ^ r8;

  // each wave stages 16 A-rows + 16 B-rows (2 GLL each)
  const u16* gA0 = Ah + (long)(m0 + wave * 16 + r8) * FFNq + cl * 8;
  const u16* gA1 = gA0 + 8 * FFNq;
  const u16* gB0 = Bh + (long)(n0 + wave * 16 + r8) * FFNq + cl * 8;
  const u16* gB1 = gB0 + 8 * FFNq;
  const int lA0 = (wave * 16) * 64, lA1 = lA0 + 512;
  const int lB0 = 8192 + (wave * 16) * 64, lB1 = lB0 + 512;

  u16* cur = lds;
  u16* nxt = lds + 16384;

  // prologue prefetch
  GLL(gA0, cur + lA0); GLL(gA1, cur + lA1);
  GLL(gB0, cur + lB0); GLL(gB1, cur + lB1);
  gA0 += 64; gA1 += 64; gB0 += 64; gB1 += 64;

  f32x4 acc[4][2] = {};
  for (int it = 0; it < FFNq / 64; ++it) {
    __syncthreads();
    if (it < FFNq / 64 - 1) {
      GLL(gA0, nxt + lA0); GLL(gA1, nxt + lA1);
      GLL(gB0, nxt + lB0); GLL(gB1, nxt + lB1);
      gA0 += 64; gA1 += 64; gB0 += 64; gB1 += 64;
    }
    u16* La = cur;
    u16* Lb = cur + 8192;
#pragma unroll
    for (int c = 0; c < 2; ++c) {
      const int sw = ((c * 4 + quad) ^ (n & 7)) * 8;
      f16x8 af[4], bf[2];
#pragma unroll
      for (int i = 0; i < 4; ++i)
        af[i] = *(const f16x8*)(La + (wm * 64 + i * 16 + n) * 64 + sw);
#pragma unroll
      for (int j = 0; j < 2; ++j)
        bf[j] = *(const f16x8*)(Lb + (wn * 32 + j * 16 + n) * 64 + sw);
#pragma unroll
      for (int i = 0; i < 4; ++i)
#pragma unroll
        for (int j = 0; j < 2; ++j) acc[i][j] = MFMA(af[i], bf[j], acc[i][j]);
    }
    u16* t = cur; cur = nxt; nxt = t;
  }
#pragma unroll
  for (int i = 0; i < 4; ++i) {
    const int row = m0 + wm * 64 + i * 16 + quad * 4;
#pragma unroll
    for (int j = 0; j < 2; ++j) {
      u16* cp = C + (long)row * Eq + n0 + wn * 32 + j * 16 + n;
      cp[0] = f2h(acc[i][j][0]);
      cp[Eq] = f2h(acc[i][j][1]);
      cp[2 * Eq] = f2h(acc[i][j][2]);
      cp[3 * Eq] = f2h(acc[i][j][3]);
    }
  }
}

// ---------------- LN2: out = LN(h + ffn + b2), fp32 out ----------------
__global__ void k_ln2(const u16* __restrict__ hin, const u16* __restrict__ ffn,
                      const float* __restrict__ b2, const float* __restrict__ g,
                      const float* __restrict__ be, float* __restrict__ out) {
  const long t = blockIdx.x;
  const int tid = threadIdx.x;
  uint2 hw = ((const uint2*)(hin + t * Eq))[tid];
  uint2 fw = ((const uint2*)(ffn + t * Eq))[tid];
  float4 b2v = ((const float4*)b2)[tid];
  float v0 = h2f(hw.x & 0xffff) + h2f(fw.x & 0xffff) + b2v.x;
  float v1 = h2f(hw.x >> 16) + h2f(fw.x >> 16) + b2v.y;
  float v2 = h2f(hw.y & 0xffff) + h2f(fw.y & 0xffff) + b2v.z;
  float v3 = h2f(hw.y >> 16) + h2f(fw.y >> 16) + b2v.w;
  float s = (v0 + v1) + (v2 + v3);
  float s2 = v0 * v0 + v1 * v1 + v2 * v2 + v3 * v3;
#pragma unroll
  for (int o = 1; o < 64; o <<= 1) {
    s += __shfl_xor(s, o);
    s2 += __shfl_xor(s2, o);
  }
  __shared__ float red[8];
  const int wv = tid >> 6, ln = tid & 63;
  if (ln == 0) { red[wv] = s; red[4 + wv] = s2; }
  __syncthreads();
  s = red[0] + red[1] + red[2] + red[3];
  s2 = red[4] + red[5] + red[6] + red[7];
  const float mu = s * (1.f / Eq);
  const float var = s2 * (1.f / Eq) - mu * mu;
  const float rstd = rsqrtf(var + 1e-5f);
  float4 gv = ((const float4*)g)[tid];
  float4 bv = ((const float4*)be)[tid];
  float4 o;
  o.x = (v0 - mu) * rstd * gv.x + bv.x;
  o.y = (v1 - mu) * rstd * gv.y + bv.y;
  o.z = (v2 - mu) * rstd * gv.z + bv.z;
  o.w = (v3 - mu) * rstd * gv.w + bv.w;
  ((float4*)(out + t * Eq))[tid] = o;
}

extern "C" void kernel_launch(void* const* d_in, const int* in_sizes, int n_in,
                              void* d_out, int out_size, void* d_ws, size_t ws_size,
                              hipStream_t stream) {
  const float* x = (const float*)d_in[0];
  const float* theta = (const float*)d_in[1];
  const float* w1 = (const float*)d_in[2];
  const float* b1 = (const float*)d_in[3];
  const float* w2 = (const float*)d_in[4];
  const float* b2 = (const float*)d_in[5];
  const float* g1 = (const float*)d_in[6];
  const float* be1 = (const float*)d_in[7];
  const float* g2 = (const float*)d_in[8];
  const float* be2 = (const float*)d_in[9];
  float* out = (float*)d_out;

  char* ws = (char*)d_ws;
  u16* attn = (u16*)(ws);                      // 16 MB
  u16* h = (u16*)(ws + 16777216);              // 16 MB
  u16* xh = (u16*)(ws + 33554432);             // 16 MB
  u16* xt = (u16*)(ws + 50331648);             // 16 MB
  u16* ffn = (u16*)(ws + 67108864);            // 16 MB
  u16* hid = (u16*)(ws + 83886080);            // 64 MB
  u16* w2h = (u16*)(ws + 150994944);           //  8 MB
  u16* qout = (u16*)(ws + 159383552);          // 128 KB

  k_prep<<<2 * Bq * Hq * (Sq / 64), 256, 0, stream>>>(x, xh, xt, w2, (uint4*)w2h);
  k_attn<<<Bq * Hq * (Sq / 256), 512, 0, stream>>>(xh, xt, attn);
  k_ln1<<<Bq * Sq, 256, 0, stream>>>(xh, attn, g1, be1, theta, h, qout);
  k_hid<<<(Bq * Sq / 256) * (FFNq / 64), 256, 0, stream>>>(qout, w1, b1, hid);
  k_gemm<<<(Bq * Sq / 128) * (Eq / 128), 512, 0, stream>>>(hid, w2h, ffn);
  k_ln2<<<Bq * Sq, 256, 0, stream>>>(h, ffn, b2, g2, be2, out);
}

// Round 8
// 285.499 us; speedup vs baseline: 1.1369x; 1.0565x over previous
//
#include <hip/hip_runtime.h>

// TransformerBlockQuantum: attention(Q=K=V=x) -> LN1 -> quantum FFN -> LN2
// Round 11: k_attn P-buffer re-laid-out with padded row stride (72 halves =
// 144B, co-prime with the 32-bank frame) and no XOR swizzle -- kills the
// 4.19M P-path bank conflicts identified in R5 while keeping the cheap LDS
// round-trip (R5's register repack cost more VALU than it saved). K/V paths
// and all other kernels identical to round 10 (best: 301.6us).

#define Bq 4
#define Sq 2048
#define Eq 1024
#define Hq 16
#define DKq 64
#define FFNq 4096
#define NQq 8
#define LOG2E 1.44269504f

typedef unsigned int u32;
typedef unsigned short u16;
typedef _Float16 f16;
typedef f16 f16x8 __attribute__((ext_vector_type(8)));
typedef __fp16 fp16x2 __attribute__((ext_vector_type(2)));
typedef float f32x4 __attribute__((ext_vector_type(4)));

#if __has_builtin(__builtin_amdgcn_exp2f)
#define EXP2F __builtin_amdgcn_exp2f
#else
#define EXP2F exp2f
#endif

#define MFMA(a, b, c) __builtin_amdgcn_mfma_f32_16x16x32_f16((a), (b), (c), 0, 0, 0)

// async global->LDS, 16B per lane; LDS dest = base + lane*16 (wave-uniform base)
#define GLL(g, l)                                                          \
  __builtin_amdgcn_global_load_lds(                                        \
      (const __attribute__((address_space(1))) u32*)(g),                   \
      (__attribute__((address_space(3))) u32*)(l), 16, 0, 0)

__device__ __forceinline__ u16 f2h(float x) {
  f16 t = (f16)x;
  return __builtin_bit_cast(u16, t);
}
__device__ __forceinline__ float h2f(u16 w) {
  return (float)__builtin_bit_cast(f16, w);
}
#if __has_builtin(__builtin_amdgcn_cvt_pkrtz)
__device__ __forceinline__ u32 pkrtz(float a, float b) {
  fp16x2 r = __builtin_amdgcn_cvt_pkrtz(a, b);
  return __builtin_bit_cast(u32, r);
}
#else
__device__ __forceinline__ u32 pkrtz(float a, float b) {
  return (u32)f2h(a) | ((u32)f2h(b) << 16);
}
#endif

union F8 { f16x8 v; u32 w[4]; u16 h[8]; f16 e[8]; };

// ------- merged prep: blocks [0,2048): x fp32 -> xh fp16 + xt fp16
//                      blocks [2048,4096): w2 fp32 -> fp16 ----------
__global__ void k_prep(const float* __restrict__ x, u16* __restrict__ xh,
                       u16* __restrict__ xt, const float* __restrict__ w2src,
                       uint4* __restrict__ w2dst) {
  __shared__ u16 tile[64 * 72];
  const int tid = threadIdx.x;
  const int bx = blockIdx.x;
  if (bx >= 2048) {
    const int i = (bx - 2048) * 256 + tid;
    const int n8 = (Eq * FFNq) / 8;
    if (i < n8) {
      const float4* s = (const float4*)w2src + 2 * (long)i;
      float4 a = s[0], b = s[1];
      uint4 r;
      r.x = pkrtz(a.x, a.y);
      r.y = pkrtz(a.z, a.w);
      r.z = pkrtz(b.x, b.y);
      r.w = pkrtz(b.z, b.w);
      w2dst[i] = r;
    }
    return;
  }
  const int sb = bx & 31, bh = bx >> 5;
  const int b = bh >> 4, h = bh & 15;
  const int s0 = sb * 64;
  const int r = tid >> 2, cq = tid & 3;
  const float* xp = x + ((long)(b * Sq + s0 + r)) * Eq + h * 64 + cq * 16;
  float4 f0 = ((const float4*)xp)[0], f1 = ((const float4*)xp)[1];
  float4 f2 = ((const float4*)xp)[2], f3 = ((const float4*)xp)[3];
  u32 w[8];
  w[0] = pkrtz(f0.x, f0.y); w[1] = pkrtz(f0.z, f0.w);
  w[2] = pkrtz(f1.x, f1.y); w[3] = pkrtz(f1.z, f1.w);
  w[4] = pkrtz(f2.x, f2.y); w[5] = pkrtz(f2.z, f2.w);
  w[6] = pkrtz(f3.x, f3.y); w[7] = pkrtz(f3.z, f3.w);
  uint4* xo = (uint4*)(xh + ((long)(b * Sq + s0 + r)) * Eq + h * 64 + cq * 16);
  xo[0] = make_uint4(w[0], w[1], w[2], w[3]);
  xo[1] = make_uint4(w[4], w[5], w[6], w[7]);
  uint4* tp = (uint4*)(tile + r * 72 + cq * 16);
  tp[0] = make_uint4(w[0], w[1], w[2], w[3]);
  tp[1] = make_uint4(w[4], w[5], w[6], w[7]);
  __syncthreads();
  const int d = tid >> 2, rq = tid & 3;
  u32 o[8];
#pragma unroll
  for (int i = 0; i < 8; ++i) {
    u32 lo = tile[(rq * 16 + 2 * i) * 72 + d];
    u32 hi = tile[(rq * 16 + 2 * i + 1) * 72 + d];
    o[i] = lo | (hi << 16);
  }
  uint4* to = (uint4*)(xt + ((long)(bh * 64 + d)) * Sq + s0 + rq * 16);
  to[0] = make_uint4(o[0], o[1], o[2], o[3]);
  to[1] = make_uint4(o[4], o[5], o[6], o[7]);
}

// ---------------- flash attention (round-4 structure + padded P) -------------
// grid 512 = qb(8) x bh(64); 8 waves / 512 threads; each wave owns 32 q-rows.
// Double-buffered K/V via GLL, ONE barrier per k-block. P buffer: row stride
// 72 halves (144B, co-prime with 32 banks) -> no XOR needed, both the uint2
// writes and b128 reads are 2-way-max per 16-lane phase (free).
__global__ __launch_bounds__(512, 4) void k_attn(const u16* __restrict__ xh,
                                                 const u16* __restrict__ xt,
                                                 u16* __restrict__ attn) {
  // 2 x (Kl 8KB | Vt 8KB) = 16384 halves; P = 8 waves x 2 nt x 16 x 72 halves
  __shared__ __align__(16) u16 lds[34816];
  u16* Pl = lds + 16384;

  const int tid = threadIdx.x;
  const int wave = tid >> 6, lane = tid & 63;
  const int n = lane & 15, quad = lane >> 4;

  const int bx = blockIdx.x;
  const int qb = bx >> 6, bh = bx & 63;
  const int b = bh >> 4, h = bh & 15;

  const u16* xh_bh = xh + (long)b * Sq * Eq + h * 64;  // row stride Eq halves
  const u16* xt_bh = xt + (long)bh * 64 * Sq;          // row stride Sq halves

  const float SC = 0.125f * LOG2E;
  F8 qf[2][2];
  float shift[2], lrow[2] = {0.f, 0.f};
#pragma unroll
  for (int nt = 0; nt < 2; ++nt) {
    const int q = qb * 256 + wave * 32 + nt * 16 + n;
    const u16* qp = xh_bh + (long)q * Eq + quad * 8;
    F8 a, c;
    a.v = *(const f16x8*)qp;
    c.v = *(const f16x8*)(qp + 32);
    float s2 = 0.f;
#pragma unroll
    for (int i = 0; i < 8; ++i) {
      float va = (float)a.e[i], vc = (float)c.e[i];
      s2 += va * va + vc * vc;
      qf[nt][0].e[i] = a.e[i] * (f16)SC;
      qf[nt][1].e[i] = c.e[i] * (f16)SC;
    }
    s2 += __shfl_xor(s2, 16);
    s2 += __shfl_xor(s2, 32);
    shift[nt] = SC * s2;  // diagonal score in log2 domain
  }

  const int r8 = lane >> 3;
  const int cl = (lane & 7) ^ r8;
  const u16* gK = xh_bh + (long)(wave * 8 + r8) * Eq + cl * 8;
  const u16* gV = xt_bh + (long)(wave * 8 + r8) * Sq + cl * 8;
  const int lK = wave * 512;
  const int lV = 4096 + wave * 512;

  u16* cur = lds;
  u16* nxt = lds + 8192;

  GLL(gK, cur + lK);
  GLL(gV, cur + lV);
  gK += 64 * Eq;
  gV += 64;

  f32x4 O[2][4] = {};
  u16* Pw = Pl + wave * 2304;  // 2 nt x 16 rows x 72 halves

  for (int kb = 0; kb < Sq / 64; ++kb) {
    __syncthreads();
    if (kb < Sq / 64 - 1) {
      GLL(gK, nxt + lK);
      GLL(gV, nxt + lV);
      gK += 64 * Eq;
      gV += 64;
    }
    u16* Kl = cur;
    u16* Vt = cur + 4096;

    f32x4 ST[2][4];
#pragma unroll
    for (int nt = 0; nt < 2; ++nt) {
      const float ms = -shift[nt];
#pragma unroll
      for (int mt = 0; mt < 4; ++mt) {
        ST[nt][mt][0] = ms; ST[nt][mt][1] = ms;
        ST[nt][mt][2] = ms; ST[nt][mt][3] = ms;
      }
    }
    __builtin_amdgcn_s_setprio(1);
#pragma unroll
    for (int mt = 0; mt < 4; ++mt) {
#pragma unroll
      for (int c = 0; c < 2; ++c) {
        f16x8 af = *(const f16x8*)(Kl + (mt * 16 + n) * 64 +
                                   (((c * 4 + quad) ^ (n & 7)) * 8));
#pragma unroll
        for (int nt = 0; nt < 2; ++nt)
          ST[nt][mt] = MFMA(af, qf[nt][c].v, ST[nt][mt]);
      }
    }
    __builtin_amdgcn_s_setprio(0);

#pragma unroll
    for (int nt = 0; nt < 2; ++nt) {
      float ls = 0.f;
#pragma unroll
      for (int mt = 0; mt < 4; ++mt) {
        float p0 = EXP2F(ST[nt][mt][0]);
        float p1 = EXP2F(ST[nt][mt][1]);
        float p2 = EXP2F(ST[nt][mt][2]);
        float p3 = EXP2F(ST[nt][mt][3]);
        ls += (p0 + p1) + (p2 + p3);
        const int ch = 2 * mt + (quad >> 1);
        *(uint2*)(Pw + nt * 1152 + n * 72 + ch * 8 + (quad & 1) * 4) =
            make_uint2(pkrtz(p0, p1), pkrtz(p2, p3));
      }
      lrow[nt] += ls;
    }

    __builtin_amdgcn_s_setprio(1);
#pragma unroll
    for (int c = 0; c < 2; ++c) {
      const int pc = (c * 4 + quad) * 8;
      f16x8 pf[2];
#pragma unroll
      for (int nt = 0; nt < 2; ++nt)
        pf[nt] = *(const f16x8*)(Pw + nt * 1152 + n * 72 + pc);
      const int vc = ((c * 4 + quad) ^ (n & 7)) * 8;
#pragma unroll
      for (int dt = 0; dt < 4; ++dt) {
        f16x8 vf = *(const f16x8*)(Vt + (dt * 16 + n) * 64 + vc);
#pragma unroll
        for (int nt = 0; nt < 2; ++nt) O[nt][dt] = MFMA(vf, pf[nt], O[nt][dt]);
      }
    }
    __builtin_amdgcn_s_setprio(0);
    u16* t = cur; cur = nxt; nxt = t;
  }

#pragma unroll
  for (int nt = 0; nt < 2; ++nt) {
    float l = lrow[nt];
    l += __shfl_xor(l, 16);
    l += __shfl_xor(l, 32);
    const float inv = 1.0f / l;
    const int q = qb * 256 + wave * 32 + nt * 16 + n;
    u16* op = attn + (long)b * Sq * Eq + (long)q * Eq + h * 64;
#pragma unroll
    for (int dt = 0; dt < 4; ++dt) {
      u32 w0 = pkrtz(O[nt][dt][0] * inv, O[nt][dt][1] * inv);
      u32 w1 = pkrtz(O[nt][dt][2] * inv, O[nt][dt][3] * inv);
      *(uint2*)(op + dt * 16 + quad * 4) = make_uint2(w0, w1);
    }
  }
}

// ---------------- LN1 (+residual) + quantum qout (all fp16 IO) ----------------
__global__ void k_ln1(const u16* __restrict__ xh, const u16* __restrict__ attn,
                      const float* __restrict__ g, const float* __restrict__ be,
                      const float* __restrict__ theta, u16* __restrict__ hout,
                      u16* __restrict__ qout) {
  const long t = blockIdx.x;
  const int tid = threadIdx.x;
  uint2 xw = ((const uint2*)(xh + t * Eq))[tid];
  uint2 aw = ((const uint2*)(attn + t * Eq))[tid];
  float v0 = h2f(xw.x & 0xffff) + h2f(aw.x & 0xffff);
  float v1 = h2f(xw.x >> 16) + h2f(aw.x >> 16);
  float v2 = h2f(xw.y & 0xffff) + h2f(aw.y & 0xffff);
  float v3 = h2f(xw.y >> 16) + h2f(aw.y >> 16);
  float s = (v0 + v1) + (v2 + v3);
  float s2 = v0 * v0 + v1 * v1 + v2 * v2 + v3 * v3;
#pragma unroll
  for (int o = 1; o < 64; o <<= 1) {
    s += __shfl_xor(s, o);
    s2 += __shfl_xor(s2, o);
  }
  __shared__ float red[8];
  const int wv = tid >> 6, ln = tid & 63;
  if (ln == 0) { red[wv] = s; red[4 + wv] = s2; }
  __syncthreads();
  s = red[0] + red[1] + red[2] + red[3];
  s2 = red[4] + red[5] + red[6] + red[7];
  const float mu = s * (1.f / Eq);
  const float var = s2 * (1.f / Eq) - mu * mu;
  const float rstd = rsqrtf(var + 1e-5f);
  float4 gv = ((const float4*)g)[tid];
  float4 bv = ((const float4*)be)[tid];
  float o0 = (v0 - mu) * rstd * gv.x + bv.x;
  float o1 = (v1 - mu) * rstd * gv.y + bv.y;
  float o2 = (v2 - mu) * rstd * gv.z + bv.z;
  float o3 = (v3 - mu) * rstd * gv.w + bv.w;
  ((uint2*)(hout + t * Eq))[tid] = make_uint2(pkrtz(o0, o1), pkrtz(o2, o3));
  if (tid < 2) {
    float hv[4] = {o0, o1, o2, o3};
    float q[4];
#pragma unroll
    for (int i = 0; i < 4; ++i) q[i] = cosf(hv[i]) * cosf(theta[tid * 4 + i]);
    *(uint2*)(qout + t * NQq + tid * 4) = make_uint2(pkrtz(q[0], q[1]), pkrtz(q[2], q[3]));
  }
}

// ---------------- hid = relu(qout . w1^T + b1), fp16 out ----------------
__global__ void k_hid(const u16* __restrict__ qout, const float* __restrict__ w1,
                      const float* __restrict__ b1, u16* __restrict__ hid) {
  __shared__ float qs[256][8];
  const int tid = threadIdx.x;
  const int fb = blockIdx.x & 63, tb = blockIdx.x >> 6;
  const int f0 = fb * 64, t0 = tb * 256;
  {
    uint4 qw = *(const uint4*)(qout + (long)(t0 + tid) * NQq);
    qs[tid][0] = h2f(qw.x & 0xffff); qs[tid][1] = h2f(qw.x >> 16);
    qs[tid][2] = h2f(qw.y & 0xffff); qs[tid][3] = h2f(qw.y >> 16);
    qs[tid][4] = h2f(qw.z & 0xffff); qs[tid][5] = h2f(qw.z >> 16);
    qs[tid][6] = h2f(qw.w & 0xffff); qs[tid][7] = h2f(qw.w >> 16);
  }
  __syncthreads();
  const int wave = tid >> 6, lane = tid & 63;
  const int f = f0 + lane;
  const float4* wp = (const float4*)(w1 + (long)f * NQq);
  float4 wa = wp[0], wb = wp[1];
  const float bb = b1[f];
  const int trow = wave * 64;
  u16* op = hid + (long)(t0 + trow) * FFNq + f;
#pragma unroll 4
  for (int i = 0; i < 64; ++i) {
    const float* q = qs[trow + i];
    float acc = bb + q[0] * wa.x + q[1] * wa.y + q[2] * wa.z + q[3] * wa.w +
                q[4] * wb.x + q[5] * wb.y + q[6] * wb.z + q[7] * wb.w;
    acc = fmaxf(acc, 0.f);
    op[(long)i * FFNq] = f2h(acc);
  }
}

// ---------------- GEMM: ffn[8192,1024] = hid x w2^T, fp16 out ----------------
// 128x128 tile, BK=64, double-buffered GLL, one barrier per k-iter.
// 8 waves / 512 threads (wave tile 64x32) -> 16 waves/CU at 64KB LDS.
// XCD swizzle: same-A blocks share bid&7 -> same XCD.
__global__ __launch_bounds__(512, 4) void k_gemm(const u16* __restrict__ Ah,
                                                 const u16* __restrict__ Bh,
                                                 u16* __restrict__ C) {
  __shared__ __align__(16) u16 lds[32768];  // 2 x (La 16KB | Lb 16KB)
  const int tid = threadIdx.x;
  const int wave = tid >> 6, lane = tid & 63;
  const int n = lane & 15, quad = lane >> 4;
  const int wm = wave >> 2, wn = wave & 3;
  const int bid = blockIdx.x;
  const int m0 = ((bid & 7) * 8 + (bid >> 6)) * 128;  // same-A blocks -> same XCD
  const int n0 = ((bid >> 3) & 7) * 128;
  const int r8 = lane >> 3;
  const int cl = (lane & 7) ^ r8;

  const u16* gA0 = Ah + (long)(m0 + wave * 16 + r8) * FFNq + cl * 8;
  const u16* gA1 = gA0 + 8 * FFNq;
  const u16* gB0 = Bh + (long)(n0 + wave * 16 + r8) * FFNq + cl * 8;
  const u16* gB1 = gB0 + 8 * FFNq;
  const int lA0 = (wave * 16) * 64, lA1 = lA0 + 512;
  const int lB0 = 8192 + (wave * 16) * 64, lB1 = lB0 + 512;

  u16* cur = lds;
  u16* nxt = lds + 16384;

  GLL(gA0, cur + lA0); GLL(gA1, cur + lA1);
  GLL(gB0, cur + lB0); GLL(gB1, cur + lB1);
  gA0 += 64; gA1 += 64; gB0 += 64; gB1 += 64;

  f32x4 acc[4][2] = {};
  for (int it = 0; it < FFNq / 64; ++it) {
    __syncthreads();
    if (it < FFNq / 64 - 1) {
      GLL(gA0, nxt + lA0); GLL(gA1, nxt + lA1);
      GLL(gB0, nxt + lB0); GLL(gB1, nxt + lB1);
      gA0 += 64; gA1 += 64; gB0 += 64; gB1 += 64;
    }
    u16* La = cur;
    u16* Lb = cur + 8192;
#pragma unroll
    for (int c = 0; c < 2; ++c) {
      const int sw = ((c * 4 + quad) ^ (n & 7)) * 8;
      f16x8 af[4], bf[2];
#pragma unroll
      for (int i = 0; i < 4; ++i)
        af[i] = *(const f16x8*)(La + (wm * 64 + i * 16 + n) * 64 + sw);
#pragma unroll
      for (int j = 0; j < 2; ++j)
        bf[j] = *(const f16x8*)(Lb + (wn * 32 + j * 16 + n) * 64 + sw);
#pragma unroll
      for (int i = 0; i < 4; ++i)
#pragma unroll
        for (int j = 0; j < 2; ++j) acc[i][j] = MFMA(af[i], bf[j], acc[i][j]);
    }
    u16* t = cur; cur = nxt; nxt = t;
  }
#pragma unroll
  for (int i = 0; i < 4; ++i) {
    const int row = m0 + wm * 64 + i * 16 + quad * 4;
#pragma unroll
    for (int j = 0; j < 2; ++j) {
      u16* cp = C + (long)row * Eq + n0 + wn * 32 + j * 16 + n;
      cp[0] = f2h(acc[i][j][0]);
      cp[Eq] = f2h(acc[i][j][1]);
      cp[2 * Eq] = f2h(acc[i][j][2]);
      cp[3 * Eq] = f2h(acc[i][j][3]);
    }
  }
}

// ---------------- LN2: out = LN(h + ffn + b2), fp32 out ----------------
__global__ void k_ln2(const u16* __restrict__ hin, const u16* __restrict__ ffn,
                      const float* __restrict__ b2, const float* __restrict__ g,
                      const float* __restrict__ be, float* __restrict__ out) {
  const long t = blockIdx.x;
  const int tid = threadIdx.x;
  uint2 hw = ((const uint2*)(hin + t * Eq))[tid];
  uint2 fw = ((const uint2*)(ffn + t * Eq))[tid];
  float4 b2v = ((const float4*)b2)[tid];
  float v0 = h2f(hw.x & 0xffff) + h2f(fw.x & 0xffff) + b2v.x;
  float v1 = h2f(hw.x >> 16) + h2f(fw.x >> 16) + b2v.y;
  float v2 = h2f(hw.y & 0xffff) + h2f(fw.y & 0xffff) + b2v.z;
  float v3 = h2f(hw.y >> 16) + h2f(fw.y >> 16) + b2v.w;
  float s = (v0 + v1) + (v2 + v3);
  float s2 = v0 * v0 + v1 * v1 + v2 * v2 + v3 * v3;
#pragma unroll
  for (int o = 1; o < 64; o <<= 1) {
    s += __shfl_xor(s, o);
    s2 += __shfl_xor(s2, o);
  }
  __shared__ float red[8];
  const int wv = tid >> 6, ln = tid & 63;
  if (ln == 0) { red[wv] = s; red[4 + wv] = s2; }
  __syncthreads();
  s = red[0] + red[1] + red[2] + red[3];
  s2 = red[4] + red[5] + red[6] + red[7];
  const float mu = s * (1.f / Eq);
  const float var = s2 * (1.f / Eq) - mu * mu;
  const float rstd = rsqrtf(var + 1e-5f);
  float4 gv = ((const float4*)g)[tid];
  float4 bv = ((const float4*)be)[tid];
  float4 o;
  o.x = (v0 - mu) * rstd * gv.x + bv.x;
  o.y = (v1 - mu) * rstd * gv.y + bv.y;
  o.z = (v2 - mu) * rstd * gv.z + bv.z;
  o.w = (v3 - mu) * rstd * gv.w + bv.w;
  ((float4*)(out + t * Eq))[tid] = o;
}

extern "C" void kernel_launch(void* const* d_in, const int* in_sizes, int n_in,
                              void* d_out, int out_size, void* d_ws, size_t ws_size,
                              hipStream_t stream) {
  const float* x = (const float*)d_in[0];
  const float* theta = (const float*)d_in[1];
  const float* w1 = (const float*)d_in[2];
  const float* b1 = (const float*)d_in[3];
  const float* w2 = (const float*)d_in[4];
  const float* b2 = (const float*)d_in[5];
  const float* g1 = (const float*)d_in[6];
  const float* be1 = (const float*)d_in[7];
  const float* g2 = (const float*)d_in[8];
  const float* be2 = (const float*)d_in[9];
  float* out = (float*)d_out;

  char* ws = (char*)d_ws;
  u16* attn = (u16*)(ws);                      // 16 MB
  u16* h = (u16*)(ws + 16777216);              // 16 MB
  u16* xh = (u16*)(ws + 33554432);             // 16 MB
  u16* xt = (u16*)(ws + 50331648);             // 16 MB
  u16* ffn = (u16*)(ws + 67108864);            // 16 MB
  u16* hid = (u16*)(ws + 83886080);            // 64 MB
  u16* w2h = (u16*)(ws + 150994944);           //  8 MB
  u16* qout = (u16*)(ws + 159383552);          // 128 KB

  k_prep<<<2 * Bq * Hq * (Sq / 64), 256, 0, stream>>>(x, xh, xt, w2, (uint4*)w2h);
  k_attn<<<Bq * Hq * (Sq / 256), 512, 0, stream>>>(xh, xt, attn);
  k_ln1<<<Bq * Sq, 256, 0, stream>>>(xh, attn, g1, be1, theta, h, qout);
  k_hid<<<(Bq * Sq / 256) * (FFNq / 64), 256, 0, stream>>>(qout, w1, b1, hid);
  k_gemm<<<(Bq * Sq / 128) * (Eq / 128), 512, 0, stream>>>(hid, w2h, ffn);
  k_ln2<<<Bq * Sq, 256, 0, stream>>>(h, ffn, b2, g2, be2, out);
}